// Round 17
// baseline (316.797 us; speedup 1.0000x reference)
//
#include <hip/hip_runtime.h>

// StackedTriConv on MI355X.
// agg[n] = (deg[n]*h[n] - sum_{e:dst=n} h[src_e]) @ Wt + deg[n]*bt
// out[n] = act(agg[n] @ Wp + bp)
// R2: binned scatter (kills 16x HBM write amplification).
// R4 (measured R13): reg-resident T/o1 + shuffle GEMV; layer 83->75.7us.
// R13 (measured R15): csr-in-LDS + fixed-cap build; layer 75.7->71.5us.
//   VGPR=40 reveals compiler serialized the 6-deep batch -> per-wave MLP ~2
//   edges; FETCH 169MB = structural floor; 2.7 TB/s delivered, latency-bound.
// R15: occupancy lever: launch_bounds (256,4)->(256,6), LCAP 2048->1408
//   (mean+12sigma) so LDS 24448B -> 6 blocks/CU (grid supplies ~6.1).

#define SHIFT 9
#define SPAN 512      // 1 << SHIFT nodes per bucket
#define MAXB 256      // max buckets (N <= 131072)
#define CHUNK 4096    // edges per binning block
#define CAP 10240     // per-bucket region capacity (mean 8192, std ~90)

// ---------------- build kernels ----------------

// 1 block: init per-bucket cursors to region bases; detect int64 vs int32.
__global__ void k_init(const unsigned int* __restrict__ ew,
                       int* __restrict__ flag, int* __restrict__ bcursor) {
  int t = threadIdx.x;
  bcursor[t] = t * CAP;
  unsigned int v = 0;
#pragma unroll
  for (int j = 0; j < 4; ++j) v |= ew[2 * (t * 4 + j) + 1];
  __shared__ unsigned int red[256];
  red[t] = v;
  __syncthreads();
  for (int s = 128; s > 0; s >>= 1) {
    if (t < s) red[t] |= red[t + s];
    __syncthreads();
  }
  if (t == 0) flag[0] = (red[0] == 0u) ? 1 : 0;  // 1 => int64
}

// Stage a 4096-edge chunk in LDS, reserve per-bucket slices directly off the
// global region cursors, write packed entries (ldst<<17 | src).
__global__ void k_bin(const void* __restrict__ edges,
                      const int* __restrict__ flag, int* __restrict__ bcursor,
                      unsigned int* __restrict__ binned, int E) {
  __shared__ unsigned int pk[CHUNK];
  __shared__ unsigned char bk[CHUNK];
  __shared__ int cnt[MAXB], bb[MAXB], cnt2[MAXB];
  int t = threadIdx.x;
  cnt[t] = 0;
  cnt2[t] = 0;
  __syncthreads();
  int base = blockIdx.x * CHUNK;
  if (flag[0]) {
    const long long* p = (const long long*)edges;
#pragma unroll
    for (int j = 0; j < CHUNK / 256; ++j) {
      int li = j * 256 + t, idx = base + li;
      if (idx < E) {
        int s = (int)p[idx];
        int d = (int)p[E + idx];
        int b = d >> SHIFT;
        pk[li] = ((unsigned)(d & (SPAN - 1)) << 17) | (unsigned)s;
        bk[li] = (unsigned char)b;
        atomicAdd(&cnt[b], 1);
      }
    }
  } else {
    const int* p = (const int*)edges;
#pragma unroll
    for (int j = 0; j < CHUNK / 256; ++j) {
      int li = j * 256 + t, idx = base + li;
      if (idx < E) {
        int s = p[idx];
        int d = p[E + idx];
        int b = d >> SHIFT;
        pk[li] = ((unsigned)(d & (SPAN - 1)) << 17) | (unsigned)s;
        bk[li] = (unsigned char)b;
        atomicAdd(&cnt[b], 1);
      }
    }
  }
  __syncthreads();
  if (cnt[t]) bb[t] = atomicAdd(&bcursor[t], cnt[t]);
  __syncthreads();
#pragma unroll
  for (int j = 0; j < CHUNK / 256; ++j) {
    int li = j * 256 + t, idx = base + li;
    if (idx < E) {
      int b = bk[li];
      int r = atomicAdd(&cnt2[b], 1);
      binned[bb[b] + r] = pk[li];
    }
  }
}

// One block per bucket: local deg -> LDS scan -> offs/ends; scatter src into
// the bucket's fixed csr region (L2-local).
__launch_bounds__(256) __global__
void k_bcsr(const unsigned int* __restrict__ binned,
            const int* __restrict__ bcursor, int* __restrict__ offs,
            int* __restrict__ ends, int* __restrict__ csr, int N) {
  __shared__ int deg[SPAN];
  __shared__ int gs[128];
  __shared__ int cur[SPAN];
  int b = blockIdx.x;
  int t = threadIdx.x;
  deg[t] = 0;
  deg[t + 256] = 0;
  __syncthreads();
  int base = b * CAP;
  int cnt = bcursor[b] - base;
  for (int e = t; e < cnt; e += 256)
    atomicAdd(&deg[binned[base + e] >> 17], 1);
  __syncthreads();
  if (t < 128) gs[t] = deg[4 * t] + deg[4 * t + 1] + deg[4 * t + 2] + deg[4 * t + 3];
  __syncthreads();
  for (int off = 1; off < 128; off <<= 1) {
    int add = (t < 128 && t >= off) ? gs[t - off] : 0;
    __syncthreads();
    if (t < 128) gs[t] += add;
    __syncthreads();
  }
  int nodeBase = b << SHIFT;
  if (t < 128) {
    int run = (t == 0) ? 0 : gs[t - 1];
#pragma unroll
    for (int j = 0; j < 4; ++j) {
      int li = 4 * t + j;
      cur[li] = run;
      int node = nodeBase + li;
      if (node < N) {
        offs[node] = base + run;
        ends[node] = base + run + deg[li];
      }
      run += deg[li];
    }
  }
  __syncthreads();
  for (int e = t; e < cnt; e += 256) {
    unsigned int v = binned[base + e];
    int ld = v >> 17;
    int pos = atomicAdd(&cur[ld], 1);
    csr[base + pos] = (int)(v & 0x1FFFFu);
  }
}

// ---------------- fused layer kernel ----------------
// 256 threads = 64 nodes x 4 lanes. Block's csr slice staged in LDS (it is
// contiguous: blocks never span bucket regions since SPAN%NPB==0). T and o1
// stay in registers; dual GEMV via width-4 shuffles (compile-time lane/idx).
// launch_bounds(256,6): 6 blocks/CU (LDS 24448B each), grid gives ~6.1.
template <int CIN, int COUT, int ACT>  // ACT: 0 = relu, 1 = softmax
__launch_bounds__(256, 6) __global__
void k_layer(const float* __restrict__ hin, float* __restrict__ hout,
             const int* __restrict__ offs, const int* __restrict__ ends,
             const int* __restrict__ csr,
             const float* __restrict__ Wt, const float* __restrict__ bt,
             const float* __restrict__ Wp, const float* __restrict__ bp,
             int n) {
  constexpr int NPB = 64;
  constexpr int NCK = CIN / 16;   // float4 chunks per thread per row
  constexpr int TCH = NCK * 4;    // channels per thread, phase 1
  constexpr int CH2 = COUT / 4;   // channels per thread, phases 2-3
  constexpr int LCAP = 1408;      // block csr slice cap (mean 1024, +12sigma)

  __shared__ float Wtl[CIN * COUT];
  __shared__ float Wpl[COUT * COUT];
  __shared__ float btl[COUT];
  __shared__ float bpl[COUT];
  __shared__ int lcsr[LCAP];

  int t = threadIdx.x;
  for (int i = t; i < CIN * COUT; i += 256) Wtl[i] = Wt[i];
  for (int i = t; i < COUT * COUT; i += 256) Wpl[i] = Wp[i];
  if (t < COUT) {
    btl[t] = bt[t];
    bpl[t] = bp[t];
  }

  int nf = blockIdx.x * NPB;
  int nl = min(nf + NPB - 1, n - 1);
  int blkBase = offs[nf];
  int blkCnt = min(ends[nl] - blkBase, LCAP);
  for (int i = t; i < blkCnt; i += 256) lcsr[i] = csr[blkBase + i];
  __syncthreads();  // weights + lcsr ready

  int ln = t >> 2;
  int g = t & 3;
  int node = nf + ln;
  bool valid = node < n;
  int start = valid ? offs[node] - blkBase : 0;
  int end = valid ? ends[node] - blkBase : 0;
  float degf = (float)(end - start);

  // ---- phase 1: gather, 6 edges per batch, indices from LDS ----
  const int fo = 4 * g;
  float acc[TCH];
#pragma unroll
  for (int j = 0; j < TCH; ++j) acc[j] = 0.f;

  int k = start;
  for (; k + 5 < end; k += 6) {
    float4 v[6][NCK];
#pragma unroll
    for (int d = 0; d < 6; ++d) {
      const float* r = hin + (size_t)lcsr[k + d] * CIN + fo;
#pragma unroll
      for (int q = 0; q < NCK; ++q) v[d][q] = *(const float4*)(r + 16 * q);
    }
#pragma unroll
    for (int q = 0; q < NCK; ++q) {
#pragma unroll
      for (int d = 0; d < 6; ++d) {
        acc[q * 4 + 0] += v[d][q].x;
        acc[q * 4 + 1] += v[d][q].y;
        acc[q * 4 + 2] += v[d][q].z;
        acc[q * 4 + 3] += v[d][q].w;
      }
    }
  }
  for (; k < end; ++k) {
    const float* r = hin + (size_t)lcsr[k] * CIN + fo;
#pragma unroll
    for (int q = 0; q < NCK; ++q) {
      float4 v = *(const float4*)(r + 16 * q);
      acc[q * 4 + 0] += v.x;
      acc[q * 4 + 1] += v.y;
      acc[q * 4 + 2] += v.z;
      acc[q * 4 + 3] += v.w;
    }
  }

  // T in registers: tch[q*4+j] = channel 16q+4g+j
  float tch[TCH];
  {
    const float* me = hin + (size_t)(valid ? node : 0) * CIN + fo;
#pragma unroll
    for (int q = 0; q < NCK; ++q) {
      float4 v = *(const float4*)(me + 16 * q);
      tch[q * 4 + 0] = degf * v.x - acc[q * 4 + 0];
      tch[q * 4 + 1] = degf * v.y - acc[q * 4 + 1];
      tch[q * 4 + 2] = degf * v.z - acc[q * 4 + 2];
      tch[q * 4 + 3] = degf * v.w - acc[q * 4 + 3];
    }
  }

  // ---- phase 2: o1 = T @ Wt + deg*bt (shuffle-broadcast T) ----
  const int c2 = g * CH2;
  float a2[CH2];
#pragma unroll
  for (int j = 0; j < CH2; ++j) a2[j] = degf * btl[c2 + j];
#pragma unroll
  for (int kk = 0; kk < CIN; ++kk) {
    const int owner = (kk >> 2) & 3;
    const int idx = ((kk >> 4) << 2) | (kk & 3);
    float tv = __shfl(tch[idx], owner, 4);
#pragma unroll
    for (int j = 0; j < CH2; ++j) a2[j] += tv * Wtl[kk * COUT + c2 + j];
  }

  // ---- phase 3: o2 = o1 @ Wp + bp (shuffle-broadcast o1) ----
  float a3[CH2];
#pragma unroll
  for (int j = 0; j < CH2; ++j) a3[j] = bpl[c2 + j];
#pragma unroll
  for (int kk = 0; kk < COUT; ++kk) {
    const int owner = kk / CH2;
    const int idx = kk % CH2;
    float ov = __shfl(a2[idx], owner, 4);
#pragma unroll
    for (int j = 0; j < CH2; ++j) a3[j] += ov * Wpl[kk * COUT + c2 + j];
  }

  if (ACT == 0) {
#pragma unroll
    for (int j = 0; j < CH2; ++j) a3[j] = fmaxf(a3[j], 0.f);
  } else {
    float m = -1e30f;
#pragma unroll
    for (int j = 0; j < CH2; ++j) m = fmaxf(m, a3[j]);
    m = fmaxf(m, __shfl_xor(m, 1));
    m = fmaxf(m, __shfl_xor(m, 2));
    float ssum = 0.f;
#pragma unroll
    for (int j = 0; j < CH2; ++j) {
      a3[j] = __expf(a3[j] - m);
      ssum += a3[j];
    }
    ssum += __shfl_xor(ssum, 1);
    ssum += __shfl_xor(ssum, 2);
    float inv = 1.0f / ssum;
#pragma unroll
    for (int j = 0; j < CH2; ++j) a3[j] *= inv;
  }

  if (valid) {
    float* orow = hout + (size_t)node * COUT + c2;
#pragma unroll
    for (int q = 0; q < CH2 / 4; ++q) {
      reinterpret_cast<float4*>(orow)[q] =
          make_float4(a3[q * 4 + 0], a3[q * 4 + 1], a3[q * 4 + 2], a3[q * 4 + 3]);
    }
  }
}

// ---------------- launch ----------------

extern "C" void kernel_launch(void* const* d_in, const int* in_sizes, int n_in,
                              void* d_out, int out_size, void* d_ws,
                              size_t ws_size, hipStream_t stream) {
  const float* f = (const float*)d_in[0];
  const void* edges = d_in[1];
  const float* Wt1 = (const float*)d_in[2];
  const float* bt1 = (const float*)d_in[3];
  const float* Wp1 = (const float*)d_in[4];
  const float* bp1 = (const float*)d_in[5];
  const float* Wt2 = (const float*)d_in[6];
  const float* bt2 = (const float*)d_in[7];
  const float* Wp2 = (const float*)d_in[8];
  const float* bp2 = (const float*)d_in[9];
  const float* Wt3 = (const float*)d_in[10];
  const float* bt3 = (const float*)d_in[11];
  const float* Wp3 = (const float*)d_in[12];
  const float* bp3 = (const float*)d_in[13];

  const int N = in_sizes[0] / 32;          // 100000
  const int E = in_sizes[1] / 2;           // 1600000
  const int NB = (N + SPAN - 1) >> SHIFT;  // 196

  char* ws = (char*)d_ws;
  size_t o = 0;
  auto carve = [&](size_t bytes) {
    size_t r = o;
    o = (o + bytes + 255) & ~(size_t)255;
    return r;
  };
  int* flag = (int*)(ws + carve(256));
  int* bcursor = (int*)(ws + carve(MAXB * 4));
  int* offs = (int*)(ws + carve((size_t)N * 4));
  int* ends = (int*)(ws + carve((size_t)N * 4));
  int* csr = (int*)(ws + carve((size_t)NB * CAP * 4));
  float* h1 = (float*)(ws + carve((size_t)N * 48 * 4));
  float* h2 = (float*)(ws + carve((size_t)N * 48 * 4));
  // binned aliases h1: consumed by k_bcsr before layer 1 writes h1.
  unsigned int* binned = (unsigned int*)h1;
  (void)ws_size;

  const int nChunks = (E + CHUNK - 1) / CHUNK;  // 391

  k_init<<<1, 256, 0, stream>>>((const unsigned int*)edges, flag, bcursor);
  k_bin<<<nChunks, 256, 0, stream>>>(edges, flag, bcursor, binned, E);
  k_bcsr<<<NB, 256, 0, stream>>>(binned, bcursor, offs, ends, csr, N);

  const int nbl = (N + 63) / 64;  // 1563
  k_layer<32, 48, 0><<<nbl, 256, 0, stream>>>(f, h1, offs, ends, csr, Wt1, bt1,
                                              Wp1, bp1, N);
  k_layer<48, 48, 0><<<nbl, 256, 0, stream>>>(h1, h2, offs, ends, csr, Wt2,
                                              bt2, Wp2, bp2, N);
  k_layer<48, 32, 1><<<nbl, 256, 0, stream>>>(h2, (float*)d_out, offs, ends,
                                              csr, Wt3, bt3, Wp3, bp3, N);
}